// Round 15
// baseline (608.682 us; speedup 1.0000x reference)
//
#include <hip/hip_runtime.h>
#include <hip/hip_bf16.h>
#include <math.h>

#define HID 512
#define WCW_LD 576
#define LEAF 4681

typedef unsigned short u16;
typedef __attribute__((ext_vector_type(8))) short bf16x8;
typedef __attribute__((ext_vector_type(4))) float f32x4;

__device__ __forceinline__ u16 f2bf(float f) {
    union { float f; unsigned u; } x; x.f = f;
    unsigned r = x.u + 0x7fffu + ((x.u >> 16) & 1u);
    return (u16)(r >> 16);
}
__device__ __forceinline__ float bf2f(u16 b) {
    union { unsigned u; float f; } x; x.u = ((unsigned)b) << 16; return x.f;
}
__device__ __forceinline__ float sigm(float x) { return 1.f / (1.f + expf(-x)); }

// XOR swizzle within 128-B windows (row stride multiple of 128 B)
__device__ __forceinline__ int swz(int row, int byte) { return byte ^ ((row & 7) << 4); }

// async global->LDS, 16B per lane; LDS dest = wave-uniform base + lane*16
__device__ __forceinline__ void gload_lds16(const void* g, void* l) {
    __builtin_amdgcn_global_load_lds(
        (const __attribute__((address_space(1))) void*)g,
        (__attribute__((address_space(3))) void*)l, 16, 0, 0);
}

// ---------------------------------------------------------------------------
// Fused prologue: weight conversion (blocks 20..531) + Pe/PeT16 (blocks 0..19)
__global__ __launch_bounds__(512)
void conv_pe(const float* __restrict__ W_ih, const float* __restrict__ W_hh,
             const float* __restrict__ Wc_w, const float* __restrict__ emb,
             const float* __restrict__ Wc_b,
             u16* __restrict__ Wih16, u16* __restrict__ Whh16, u16* __restrict__ Wch16,
             float* __restrict__ Pe, u16* __restrict__ PeT16) {
    if (blockIdx.x < 20) {
        int v = blockIdx.x, j = threadIdx.x;
        __shared__ float e[64];
        if (threadIdx.x < 64) e[threadIdx.x] = emb[v * 64 + threadIdx.x];
        __syncthreads();
        float acc = Wc_b[j];
        const float* w = Wc_w + (long long)j * WCW_LD;
#pragma unroll 8
        for (int k = 0; k < 64; ++k) acc += e[k] * w[k];
        Pe[v * HID + j] = acc;
        PeT16[v * HID + j] = f2bf(tanhf(acc));
    } else {
        int idx = (blockIdx.x - 20) * 512 + threadIdx.x;
        int stride = (gridDim.x - 20) * 512;
        for (int i = idx; i < 3 * HID * HID; i += stride) {
            Wih16[i] = f2bf(W_ih[i]);
            Whh16[i] = f2bf(W_hh[i]);
        }
        for (int i = idx; i < HID * HID; i += stride) {
            int j = i >> 9, k = i & 511;
            Wch16[i] = f2bf(Wc_w[(long long)j * WCW_LD + 64 + k]);
        }
    }
}

// ---------------------------------------------------------------------------
// Gx20[v][j'] = PeT16[v] . Wih16[j'] + b_ih[j']   (fp32, 20 x 1536)
__global__ __launch_bounds__(256)
void gx20_kernel(const u16* __restrict__ PeT16, const u16* __restrict__ Wih16,
                 const float* __restrict__ b_ih, float* __restrict__ Gx20) {
    int v = blockIdx.x;
    int j = blockIdx.y * 256 + threadIdx.x;
    const u16* a = PeT16 + v * HID;
    const u16* b = Wih16 + (long long)j * HID;
    float acc = b_ih[j];
    for (int k = 0; k < HID; k += 8) {
        bf16x8 av = *(const bf16x8*)(a + k);
        bf16x8 bv = *(const bf16x8*)(b + k);
#pragma unroll
        for (int i = 0; i < 8; ++i) acc += bf2f((u16)av[i]) * bf2f((u16)bv[i]);
    }
    Gx20[v * 1536 + j] = acc;
}

// H1[v] = GRU step-0 output given gx = Gx20[v]  (h_prev = 0)
__global__ void h1_kernel(const float* __restrict__ Gx20, const float* __restrict__ b_hh,
                          float* __restrict__ H1f, u16* __restrict__ H1_16) {
    int v = blockIdx.x, j = threadIdx.x;
    float xr = Gx20[v * 1536 + j], xz = Gx20[v * 1536 + 512 + j], xn = Gx20[v * 1536 + 1024 + j];
    float r = sigm(xr + b_hh[j]);
    float z = sigm(xz + b_hh[HID + j]);
    float cand = tanhf(xn + r * b_hh[2 * HID + j]);
    float h = (1.f - z) * cand;
    H1f[v * HID + j] = h;
    H1_16[v * HID + j] = f2bf(h);
}

// ---------------------------------------------------------------------------
// G = A @ W^T + bias -> [M x 1536], bf16 or fp32 out. 128x64 tile, 4 waves.
template<bool F32OUT>
__global__ __launch_bounds__(256)
void gx_gemm(const u16* __restrict__ Asrc, const u16* __restrict__ W16,
             const float* __restrict__ bias, u16* __restrict__ g16,
             float* __restrict__ gf, int M) {
    __shared__ __align__(16) uint8_t sA[128 * 128];
    __shared__ __align__(16) uint8_t sB[64 * 128];
    int tid = threadIdx.x, lane = tid & 63, w = tid >> 6;
    int j0 = blockIdx.x * 64;
    int m0 = blockIdx.y * 128;

    f32x4 acc[2][4];
#pragma unroll
    for (int m = 0; m < 2; ++m)
#pragma unroll
        for (int jf = 0; jf < 4; ++jf) acc[m][jf] = (f32x4){0.f, 0.f, 0.f, 0.f};

    for (int k0 = 0; k0 < HID; k0 += 64) {
#pragma unroll
        for (int l = 0; l < 4; ++l) {
            int e = tid + l * 256;
            int r = e >> 3, c = e & 7;
            int gm = m0 + r;
            uint4 v = make_uint4(0u, 0u, 0u, 0u);
            if (gm < M) v = *(const uint4*)(Asrc + (long long)gm * HID + k0 + c * 8);
            *(uint4*)(sA + r * 128 + swz(r, c * 16)) = v;
        }
#pragma unroll
        for (int l = 0; l < 2; ++l) {
            int e = tid + l * 256;
            int r = e >> 3, c = e & 7;
            uint4 v = *(const uint4*)(W16 + (long long)(j0 + r) * HID + k0 + c * 8);
            *(uint4*)(sB + r * 128 + swz(r, c * 16)) = v;
        }
        __syncthreads();
#pragma unroll
        for (int ks = 0; ks < 2; ++ks) {
            int kb = ks * 64 + ((lane >> 4) << 4);
            int ar = lane & 15;
            bf16x8 a0 = *(const bf16x8*)(sA + (w * 32 + ar) * 128 + swz(ar, kb));
            bf16x8 a1 = *(const bf16x8*)(sA + (w * 32 + 16 + ar) * 128 + swz(ar, kb));
#pragma unroll
            for (int jf = 0; jf < 4; ++jf) {
                bf16x8 b = *(const bf16x8*)(sB + (jf * 16 + ar) * 128 + swz(ar, kb));
                acc[0][jf] = __builtin_amdgcn_mfma_f32_16x16x32_bf16(a0, b, acc[0][jf], 0, 0, 0);
                acc[1][jf] = __builtin_amdgcn_mfma_f32_16x16x32_bf16(a1, b, acc[1][jf], 0, 0, 0);
            }
        }
        __syncthreads();
    }

#pragma unroll
    for (int jf = 0; jf < 4; ++jf) {
        int j = j0 + jf * 16 + (lane & 15);
        float bv = bias[j];
#pragma unroll
        for (int m = 0; m < 2; ++m) {
#pragma unroll
            for (int q = 0; q < 4; ++q) {
                int row = m0 + w * 32 + m * 16 + (lane >> 4) * 4 + q;
                if (row < M) {
                    float val = acc[m][jf][q] + bv;
                    if (F32OUT) gf[(long long)row * 1536 + j] = val;
                    else        g16[(long long)row * 1536 + j] = f2bf(val);
                }
            }
        }
    }
}

// ---------------------------------------------------------------------------
// h2 table: pair pr = v0*20+v1: h2 = GRU(gx=Gx20[v1], gh=Gh1[v0], hp=H1f[v0])
__global__ __launch_bounds__(256)
void h2_expand(const float* __restrict__ Gx20, const float* __restrict__ Gh1,
               const float* __restrict__ H1f, float* __restrict__ h2f,
               u16* __restrict__ h2_16) {
    int idx = blockIdx.x * 256 + threadIdx.x;   // 400*512
    int pr = idx >> 9, j = idx & 511;
    int v0 = pr / 20, v1 = pr % 20;
    const float* gx = Gx20 + (long long)v1 * 1536 + j;
    const float* gh = Gh1 + (long long)v0 * 1536 + j;
    float r = sigm(gx[0] + gh[0]);
    float z = sigm(gx[512] + gh[512]);
    float cand = tanhf(gx[1024] + r * gh[1024]);
    float h = (1.f - z) * cand + z * H1f[(long long)v0 * HID + j];
    h2f[(long long)pr * HID + j] = h;
    h2_16[(long long)pr * HID + j] = f2bf(h);
}

// h3 per parent: p -> (v0,v1,v2); h3 = GRU(gx=Gx20[v2], gh=Gh2[pr], hp=h2f[pr])
__global__ __launch_bounds__(256)
void h3_expand(const float* __restrict__ Gx20, const float* __restrict__ Gh2,
               const float* __restrict__ h2f, const int* __restrict__ nt,
               float* __restrict__ hdst_f, u16* __restrict__ hdst16) {
    int idx = blockIdx.x * 256 + threadIdx.x;   // 4096*512
    int p = idx >> 9, j = idx & 511;
    int v0 = nt[LEAF + p * 8], v1 = nt[LEAF + p * 8 + 1], v2 = nt[LEAF + p * 8 + 2];
    int pr = v0 * 20 + v1;
    const float* gx = Gx20 + (long long)v2 * 1536 + j;
    const float* gh = Gh2 + (long long)pr * 1536 + j;
    float r = sigm(gx[0] + gh[0]);
    float z = sigm(gx[512] + gh[512]);
    float cand = tanhf(gx[1024] + r * gh[1024]);
    float h = (1.f - z) * cand + z * h2f[(long long)pr * HID + j];
    hdst_f[(long long)p * HID + j] = h;
    hdst16[(long long)p * HID + j] = f2bf(h);
}

// ---------------------------------------------------------------------------
// Fused h-side GRU step, PROWS-row p-tile, async global_load_lds staging.
// LDS stored LINEAR; global source pre-swizzled (col_chunk ^= lane>>3);
// reads use swz() — net effect identical to the old swizzled store.
// REQUIRES n % PROWS == 0 (no row masking on the async path).
template<int GX_TABLE, int PROWS>
__global__ __launch_bounds__(256, 4)
void step32(const u16* __restrict__ hsrc16, const float* __restrict__ hsrc_f,
            const float* __restrict__ Gx20, const u16* __restrict__ gx16, int t,
            const int* __restrict__ nt,
            float* __restrict__ hdst_f, u16* __restrict__ hdst16,
            const u16* __restrict__ Whh16, const float* __restrict__ b_hh, int n) {
    constexpr int MT = PROWS / 16;
    constexpr int ACH = PROWS / 8;        // 1KB chunks for A
    constexpr int TOT = ACH + 24;         // + 3 gates x 8 chunks
    constexpr int NIT = (TOT + 3) / 4;
    __shared__ __align__(16) uint8_t sA[PROWS * 128];
    __shared__ __align__(16) uint8_t sB[3][64 * 128];
    int tid = threadIdx.x, lane = tid & 63, w = tid >> 6;
    int p0 = blockIdx.x * PROWS, j0 = blockIdx.y * 64;
    int ar = lane & 15;
    int rsub = lane >> 3;                 // row within 8-row chunk
    int cswb = ((lane & 7) ^ rsub) * 16;  // pre-swizzled source byte offset

    f32x4 acc[3][MT];
#pragma unroll
    for (int g = 0; g < 3; ++g)
#pragma unroll
        for (int m = 0; m < MT; ++m) acc[g][m] = (f32x4){0.f, 0.f, 0.f, 0.f};

    for (int kt = 0; kt < 8; ++kt) {
        int k0 = kt * 64;
#pragma unroll
        for (int i = 0; i < NIT; ++i) {
            int ch = w + 4 * i;
            if (ch < TOT) {
                const u16* grow;
                uint8_t* ldst;
                if (ch < ACH) {
                    grow = hsrc16 + (long long)(p0 + ch * 8 + rsub) * HID + k0;
                    ldst = sA + ch * 1024;
                } else {
                    int bi = ch - ACH, g = bi >> 3, r8 = bi & 7;
                    grow = Whh16 + (long long)(g * HID + j0 + r8 * 8 + rsub) * HID + k0;
                    ldst = sB[g] + r8 * 1024;
                }
                gload_lds16((const uint8_t*)grow + cswb, ldst);
            }
        }
        __syncthreads();
#pragma unroll
        for (int ks = 0; ks < 2; ++ks) {
            int kb = ks * 64 + ((lane >> 4) << 4);
            bf16x8 a[MT];
#pragma unroll
            for (int m = 0; m < MT; ++m)
                a[m] = *(const bf16x8*)(sA + (m * 16 + ar) * 128 + swz(ar, kb));
#pragma unroll
            for (int g = 0; g < 3; ++g) {
                bf16x8 b = *(const bf16x8*)(sB[g] + (w * 16 + ar) * 128 + swz(ar, kb));
#pragma unroll
                for (int m = 0; m < MT; ++m)
                    acc[g][m] = __builtin_amdgcn_mfma_f32_16x16x32_bf16(a[m], b, acc[g][m], 0, 0, 0);
            }
        }
        __syncthreads();
    }

    int jj = j0 + w * 16 + ar;
    float bhr = b_hh[jj], bhz = b_hh[HID + jj], bhn = b_hh[2 * HID + jj];
#pragma unroll
    for (int m = 0; m < MT; ++m) {
#pragma unroll
        for (int q = 0; q < 4; ++q) {
            int p = p0 + m * 16 + (lane >> 4) * 4 + q;
            if (p >= n) continue;
            float xr, xz, xn;
            if (GX_TABLE) {
                int v = nt[LEAF + p * 8 + t];
                const float* gp = Gx20 + (long long)v * 1536 + jj;
                xr = gp[0]; xz = gp[512]; xn = gp[1024];
            } else {
                long long gb = ((long long)(p * 8 + t)) * 1536 + jj;
                xr = bf2f(gx16[gb]); xz = bf2f(gx16[gb + 512]); xn = bf2f(gx16[gb + 1024]);
            }
            float r = sigm(xr + acc[0][m][q] + bhr);
            float z = sigm(xz + acc[1][m][q] + bhz);
            float cand = tanhf(xn + r * (acc[2][m][q] + bhn));
            float hp = hsrc_f[(long long)p * HID + jj];
            float hnew = (1.f - z) * cand + z * hp;
            hdst_f[(long long)p * HID + jj] = hnew;
            hdst16[(long long)p * HID + jj] = f2bf(hnew);
        }
    }
}

// ---------------------------------------------------------------------------
// Combine, PROWS-row p-tile, async staging (same scheme). n % PROWS == 0.
template<int PROWS>
__global__ __launch_bounds__(256, 4)
void combine32(const u16* __restrict__ enc_in, const u16* __restrict__ Wch16,
               const int* __restrict__ nt, int off, const float* __restrict__ Pe,
               u16* __restrict__ out16, int n) {
    constexpr int MT = PROWS / 16;
    constexpr int ACH = PROWS / 8;
    constexpr int TOT = ACH + 8;
    constexpr int NIT = (TOT + 3) / 4;
    __shared__ __align__(16) uint8_t sA[PROWS * 128];
    __shared__ __align__(16) uint8_t sB[64 * 128];
    int tid = threadIdx.x, lane = tid & 63, w = tid >> 6;
    int p0 = blockIdx.x * PROWS, j0 = blockIdx.y * 64;
    int ar = lane & 15;
    int rsub = lane >> 3;
    int cswb = ((lane & 7) ^ rsub) * 16;

    f32x4 acc[MT];
#pragma unroll
    for (int m = 0; m < MT; ++m) acc[m] = (f32x4){0.f, 0.f, 0.f, 0.f};

    for (int kt = 0; kt < 8; ++kt) {
        int k0 = kt * 64;
#pragma unroll
        for (int i = 0; i < NIT; ++i) {
            int ch = w + 4 * i;
            if (ch < TOT) {
                const u16* grow;
                uint8_t* ldst;
                if (ch < ACH) {
                    grow = enc_in + (long long)(p0 + ch * 8 + rsub) * HID + k0;
                    ldst = sA + ch * 1024;
                } else {
                    int r8 = ch - ACH;
                    grow = Wch16 + (long long)(j0 + r8 * 8 + rsub) * HID + k0;
                    ldst = sB + r8 * 1024;
                }
                gload_lds16((const uint8_t*)grow + cswb, ldst);
            }
        }
        __syncthreads();
#pragma unroll
        for (int ks = 0; ks < 2; ++ks) {
            int kb = ks * 64 + ((lane >> 4) << 4);
            bf16x8 b = *(const bf16x8*)(sB + (w * 16 + ar) * 128 + swz(ar, kb));
#pragma unroll
            for (int m = 0; m < MT; ++m) {
                bf16x8 a = *(const bf16x8*)(sA + (m * 16 + ar) * 128 + swz(ar, kb));
                acc[m] = __builtin_amdgcn_mfma_f32_16x16x32_bf16(a, b, acc[m], 0, 0, 0);
            }
        }
        __syncthreads();
    }

    int jj = j0 + w * 16 + ar;
#pragma unroll
    for (int m = 0; m < MT; ++m) {
#pragma unroll
        for (int q = 0; q < 4; ++q) {
            int p = p0 + m * 16 + (lane >> 4) * 4 + q;
            if (p >= n) continue;
            int tv = nt[off + p];
            float v = tanhf(Pe[(long long)tv * HID + jj] + acc[m][q]);
            out16[(long long)p * HID + jj] = f2bf(v);
        }
    }
}

// ---------------------------------------------------------------------------
// Step t=0 (h=0): h1 = (1-z)*cand from gx row. One thread per (p,j).
__global__ __launch_bounds__(256)
void t0_simt(const u16* __restrict__ gx16, const float* __restrict__ b_hh,
             float* __restrict__ hdst_f, u16* __restrict__ hdst16, int n) {
    int idx = blockIdx.x * 256 + threadIdx.x;
    int p = idx >> 9, j = idx & 511;
    if (p >= n) return;
    long long gb = ((long long)(p * 8)) * 1536 + j;
    float xr = bf2f(gx16[gb]), xz = bf2f(gx16[gb + 512]), xn = bf2f(gx16[gb + 1024]);
    float r = sigm(xr + b_hh[j]);
    float z = sigm(xz + b_hh[HID + j]);
    float cand = tanhf(xn + r * b_hh[2 * HID + j]);
    float h = (1.f - z) * cand;
    hdst_f[(long long)p * HID + j] = h;
    hdst16[(long long)p * HID + j] = f2bf(h);
}

// K-split SIMT GRU step (n <= 64)
__global__ __launch_bounds__(256)
void step_simt(const u16* __restrict__ gx16, int t,
               const float* __restrict__ hsrc_f, const u16* __restrict__ hsrc16,
               float* __restrict__ hdst_f, u16* __restrict__ hdst16,
               const u16* __restrict__ Whh16, const float* __restrict__ b_hh, int n) {
    int idx = blockIdx.x * 256 + threadIdx.x;
    int kc = idx & 3, pj = idx >> 2;
    int p = pj >> 9, j = pj & 511;
    if (p >= n) return;
    const u16* hp16 = hsrc16 + (long long)p * HID + kc * 128;
    const u16* w0 = Whh16 + (long long)j * HID + kc * 128;
    const u16* w1 = w0 + (long long)HID * HID;
    const u16* w2 = w1 + (long long)HID * HID;
    float a0 = 0.f, a1 = 0.f, a2 = 0.f;
#pragma unroll 4
    for (int k = 0; k < 128; k += 8) {
        bf16x8 hv = *(const bf16x8*)(hp16 + k);
        bf16x8 v0 = *(const bf16x8*)(w0 + k);
        bf16x8 v1 = *(const bf16x8*)(w1 + k);
        bf16x8 v2 = *(const bf16x8*)(w2 + k);
#pragma unroll
        for (int i = 0; i < 8; ++i) {
            float hh = bf2f((u16)hv[i]);
            a0 += hh * bf2f((u16)v0[i]);
            a1 += hh * bf2f((u16)v1[i]);
            a2 += hh * bf2f((u16)v2[i]);
        }
    }
    a0 += __shfl_xor(a0, 1); a0 += __shfl_xor(a0, 2);
    a1 += __shfl_xor(a1, 1); a1 += __shfl_xor(a1, 2);
    a2 += __shfl_xor(a2, 1); a2 += __shfl_xor(a2, 2);
    if (kc == 0) {
        long long gb = ((long long)(p * 8 + t)) * 1536 + j;
        float xr = bf2f(gx16[gb]), xz = bf2f(gx16[gb + 512]), xn = bf2f(gx16[gb + 1024]);
        float r = sigm(xr + a0 + b_hh[j]);
        float z = sigm(xz + a1 + b_hh[HID + j]);
        float cand = tanhf(xn + r * (a2 + b_hh[2 * HID + j]));
        float hp = hsrc_f[(long long)p * HID + j];
        float hnew = (1.f - z) * cand + z * hp;
        hdst_f[(long long)p * HID + j] = hnew;
        hdst16[(long long)p * HID + j] = f2bf(hnew);
    }
}

// K-split SIMT combine (n <= 64)
__global__ __launch_bounds__(256)
void combine_simt(const u16* __restrict__ h16, const u16* __restrict__ Wch16,
                  const int* __restrict__ nt, int off, const float* __restrict__ Pe,
                  u16* __restrict__ enc16, float* __restrict__ outf, int n) {
    int idx = blockIdx.x * 256 + threadIdx.x;
    int kc = idx & 3, pj = idx >> 2;
    int p = pj >> 9, j = pj & 511;
    if (p >= n) return;
    const u16* hp = h16 + (long long)p * HID + kc * 128;
    const u16* wr = Wch16 + (long long)j * HID + kc * 128;
    float a = 0.f;
#pragma unroll 4
    for (int k = 0; k < 128; k += 8) {
        bf16x8 hv = *(const bf16x8*)(hp + k);
        bf16x8 wv = *(const bf16x8*)(wr + k);
#pragma unroll
        for (int i = 0; i < 8; ++i) a += bf2f((u16)hv[i]) * bf2f((u16)wv[i]);
    }
    a += __shfl_xor(a, 1); a += __shfl_xor(a, 2);
    if (kc == 0) {
        int tv = nt[off + p];
        float v = tanhf(Pe[(long long)tv * HID + j] + a);
        enc16[(long long)p * HID + j] = f2bf(v);
        if (outf) outf[(long long)p * HID + j] = v;
    }
}

// ---------------------------------------------------------------------------
extern "C" void kernel_launch(void* const* d_in, const int* in_sizes, int n_in,
                              void* d_out, int out_size, void* d_ws, size_t ws_size,
                              hipStream_t stream) {
    const int*   nt   = (const int*)d_in[0];
    const float* emb  = (const float*)d_in[1];
    const float* Wc_w = (const float*)d_in[2];
    const float* Wc_b = (const float*)d_in[3];
    const float* W_ih = (const float*)d_in[4];
    const float* W_hh = (const float*)d_in[5];
    const float* b_ih = (const float*)d_in[6];
    const float* b_hh = (const float*)d_in[7];

    uint8_t* p = (uint8_t*)d_ws;
    u16*   gx16  = (u16*)p;   p += (size_t)4096 * 1536 * 2;    // levels 3..0
    u16*   enc16 = (u16*)p;   p += (size_t)4096 * HID * 2;
    float* hf[2]; u16* h16[2];
    hf[0]  = (float*)p; p += (size_t)4096 * HID * 4;
    hf[1]  = (float*)p; p += (size_t)4096 * HID * 4;
    h16[0] = (u16*)p;   p += (size_t)4096 * HID * 2;
    h16[1] = (u16*)p;   p += (size_t)4096 * HID * 2;
    u16*   Wih16 = (u16*)p;   p += (size_t)3 * HID * HID * 2;
    u16*   Whh16 = (u16*)p;   p += (size_t)3 * HID * HID * 2;
    u16*   Wch16 = (u16*)p;   p += (size_t)HID * HID * 2;
    float* Pe    = (float*)p; p += (size_t)20 * HID * 4;
    u16*   PeT16 = (u16*)p;   p += (size_t)20 * HID * 2;
    float* Gx20  = (float*)p; p += (size_t)20 * 1536 * 4;
    float* H1f   = (float*)p; p += (size_t)20 * HID * 4;
    u16*   H1_16 = (u16*)p;   p += (size_t)20 * HID * 2;
    float* Gh1   = (float*)p; p += (size_t)20 * 1536 * 4;
    float* Gh2   = (float*)p; p += (size_t)400 * 1536 * 4;
    float* h2f   = (float*)p; p += (size_t)400 * HID * 4;
    u16*   h2_16 = (u16*)p;   p += (size_t)400 * HID * 2;

    // prologue (3 nodes)
    conv_pe<<<532, 512, 0, stream>>>(W_ih, W_hh, Wc_w, emb, Wc_b,
                                     Wih16, Whh16, Wch16, Pe, PeT16);
    gx20_kernel<<<dim3(20, 6), 256, 0, stream>>>(PeT16, Wih16, b_ih, Gx20);
    h1_kernel<<<20, 512, 0, stream>>>(Gx20, b_hh, H1f, H1_16);

    // ---- level 4 (n = 4096): t=0,1,2 via alphabet tables; t=3..7 fused MFMA ----
    {
        int n = 4096;
        gx_gemm<true><<<dim3(24, 1), 256, 0, stream>>>(H1_16, Whh16, b_hh, nullptr, Gh1, 20);
        h2_expand<<<800, 256, 0, stream>>>(Gx20, Gh1, H1f, h2f, h2_16);
        gx_gemm<true><<<dim3(24, 4), 256, 0, stream>>>(h2_16, Whh16, b_hh, nullptr, Gh2, 400);
        h3_expand<<<8192, 256, 0, stream>>>(Gx20, Gh2, h2f, nt, hf[0], h16[0]);
        int cur = 0;
        dim3 sgrid(n / 64, 8);   // PROWS=64: halves B-side L2 traffic vs 32
        for (int t = 3; t < 8; ++t) {
            step32<1, 64><<<sgrid, 256, 0, stream>>>(h16[cur], hf[cur], Gx20, nullptr, t, nt,
                                                     hf[cur ^ 1], h16[cur ^ 1], Whh16, b_hh, n);
            cur ^= 1;
        }
        combine32<64><<<sgrid, 256, 0, stream>>>(h16[cur], Wch16, nt, 585, Pe, enc16, n);
    }

    // ---- levels 3..0 ----
    const int sizes[4] = {512, 64, 8, 1};
    const int offs[4]  = {73, 9, 1, 0};
    for (int li = 0; li < 4; ++li) {
        int n = sizes[li], off = offs[li];
        int M = n * 8;
        dim3 ggrid(24, (M + 127) / 128);
        gx_gemm<false><<<ggrid, 256, 0, stream>>>(enc16, Wih16, b_ih, gx16, nullptr, M);

        t0_simt<<<n * 2, 256, 0, stream>>>(gx16, b_hh, hf[0], h16[0], n);
        int cur = 0;
        if (n >= 512) {
            dim3 sgrid(n / 16, 8);   // PROWS=16 -> 256 blocks
            for (int t = 1; t < 8; ++t) {
                step32<0, 16><<<sgrid, 256, 0, stream>>>(h16[cur], hf[cur], nullptr, gx16, t, nt,
                                                         hf[cur ^ 1], h16[cur ^ 1], Whh16, b_hh, n);
                cur ^= 1;
            }
            combine32<16><<<sgrid, 256, 0, stream>>>(h16[cur], Wch16, nt, off, Pe, enc16, n);
        } else {
            for (int t = 1; t < 8; ++t) {
                step_simt<<<n * 8, 256, 0, stream>>>(gx16, t, hf[cur], h16[cur],
                                                     hf[cur ^ 1], h16[cur ^ 1], Whh16, b_hh, n);
                cur ^= 1;
            }
            combine_simt<<<n * 8, 256, 0, stream>>>(h16[cur], Wch16, nt, off, Pe, enc16,
                                                    (li == 3) ? (float*)d_out : (float*)0, n);
        }
    }
}

// Round 16
// 591.177 us; speedup vs baseline: 1.0296x; 1.0296x over previous
//
#include <hip/hip_runtime.h>
#include <hip/hip_bf16.h>
#include <math.h>

#define HID 512
#define WCW_LD 576
#define LEAF 4681

typedef unsigned short u16;
typedef __attribute__((ext_vector_type(8))) short bf16x8;
typedef __attribute__((ext_vector_type(4))) float f32x4;

__device__ __forceinline__ u16 f2bf(float f) {
    union { float f; unsigned u; } x; x.f = f;
    unsigned r = x.u + 0x7fffu + ((x.u >> 16) & 1u);
    return (u16)(r >> 16);
}
__device__ __forceinline__ float bf2f(u16 b) {
    union { unsigned u; float f; } x; x.u = ((unsigned)b) << 16; return x.f;
}
__device__ __forceinline__ float sigm(float x) { return 1.f / (1.f + expf(-x)); }

// XOR swizzle within 128-B windows (row stride multiple of 128 B)
__device__ __forceinline__ int swz(int row, int byte) { return byte ^ ((row & 7) << 4); }

// async global->LDS, 16B per lane; LDS dest = wave-uniform base + lane*16
__device__ __forceinline__ void gload_lds16(const void* g, void* l) {
    __builtin_amdgcn_global_load_lds(
        (const __attribute__((address_space(1))) void*)g,
        (__attribute__((address_space(3))) void*)l, 16, 0, 0);
}

// ---------------------------------------------------------------------------
// Fused prologue: weight conversion (blocks 20..531) + Pe/PeT16 (blocks 0..19)
__global__ __launch_bounds__(512)
void conv_pe(const float* __restrict__ W_ih, const float* __restrict__ W_hh,
             const float* __restrict__ Wc_w, const float* __restrict__ emb,
             const float* __restrict__ Wc_b,
             u16* __restrict__ Wih16, u16* __restrict__ Whh16, u16* __restrict__ Wch16,
             float* __restrict__ Pe, u16* __restrict__ PeT16) {
    if (blockIdx.x < 20) {
        int v = blockIdx.x, j = threadIdx.x;
        __shared__ float e[64];
        if (threadIdx.x < 64) e[threadIdx.x] = emb[v * 64 + threadIdx.x];
        __syncthreads();
        float acc = Wc_b[j];
        const float* w = Wc_w + (long long)j * WCW_LD;
#pragma unroll 8
        for (int k = 0; k < 64; ++k) acc += e[k] * w[k];
        Pe[v * HID + j] = acc;
        PeT16[v * HID + j] = f2bf(tanhf(acc));
    } else {
        int idx = (blockIdx.x - 20) * 512 + threadIdx.x;
        int stride = (gridDim.x - 20) * 512;
        for (int i = idx; i < 3 * HID * HID; i += stride) {
            Wih16[i] = f2bf(W_ih[i]);
            Whh16[i] = f2bf(W_hh[i]);
        }
        for (int i = idx; i < HID * HID; i += stride) {
            int j = i >> 9, k = i & 511;
            Wch16[i] = f2bf(Wc_w[(long long)j * WCW_LD + 64 + k]);
        }
    }
}

// ---------------------------------------------------------------------------
// Gx20[v][j'] = PeT16[v] . Wih16[j'] + b_ih[j']   (fp32, 20 x 1536)
__global__ __launch_bounds__(256)
void gx20_kernel(const u16* __restrict__ PeT16, const u16* __restrict__ Wih16,
                 const float* __restrict__ b_ih, float* __restrict__ Gx20) {
    int v = blockIdx.x;
    int j = blockIdx.y * 256 + threadIdx.x;
    const u16* a = PeT16 + v * HID;
    const u16* b = Wih16 + (long long)j * HID;
    float acc = b_ih[j];
    for (int k = 0; k < HID; k += 8) {
        bf16x8 av = *(const bf16x8*)(a + k);
        bf16x8 bv = *(const bf16x8*)(b + k);
#pragma unroll
        for (int i = 0; i < 8; ++i) acc += bf2f((u16)av[i]) * bf2f((u16)bv[i]);
    }
    Gx20[v * 1536 + j] = acc;
}

// H1[v] = GRU step-0 output given gx = Gx20[v]  (h_prev = 0)
__global__ void h1_kernel(const float* __restrict__ Gx20, const float* __restrict__ b_hh,
                          float* __restrict__ H1f, u16* __restrict__ H1_16) {
    int v = blockIdx.x, j = threadIdx.x;
    float xr = Gx20[v * 1536 + j], xz = Gx20[v * 1536 + 512 + j], xn = Gx20[v * 1536 + 1024 + j];
    float r = sigm(xr + b_hh[j]);
    float z = sigm(xz + b_hh[HID + j]);
    float cand = tanhf(xn + r * b_hh[2 * HID + j]);
    float h = (1.f - z) * cand;
    H1f[v * HID + j] = h;
    H1_16[v * HID + j] = f2bf(h);
}

// ---------------------------------------------------------------------------
// G = A @ W^T + bias -> [M x 1536], bf16 or fp32 out. 128x64 tile, 4 waves.
template<bool F32OUT>
__global__ __launch_bounds__(256)
void gx_gemm(const u16* __restrict__ Asrc, const u16* __restrict__ W16,
             const float* __restrict__ bias, u16* __restrict__ g16,
             float* __restrict__ gf, int M) {
    __shared__ __align__(16) uint8_t sA[128 * 128];
    __shared__ __align__(16) uint8_t sB[64 * 128];
    int tid = threadIdx.x, lane = tid & 63, w = tid >> 6;
    int j0 = blockIdx.x * 64;
    int m0 = blockIdx.y * 128;

    f32x4 acc[2][4];
#pragma unroll
    for (int m = 0; m < 2; ++m)
#pragma unroll
        for (int jf = 0; jf < 4; ++jf) acc[m][jf] = (f32x4){0.f, 0.f, 0.f, 0.f};

    for (int k0 = 0; k0 < HID; k0 += 64) {
#pragma unroll
        for (int l = 0; l < 4; ++l) {
            int e = tid + l * 256;
            int r = e >> 3, c = e & 7;
            int gm = m0 + r;
            uint4 v = make_uint4(0u, 0u, 0u, 0u);
            if (gm < M) v = *(const uint4*)(Asrc + (long long)gm * HID + k0 + c * 8);
            *(uint4*)(sA + r * 128 + swz(r, c * 16)) = v;
        }
#pragma unroll
        for (int l = 0; l < 2; ++l) {
            int e = tid + l * 256;
            int r = e >> 3, c = e & 7;
            uint4 v = *(const uint4*)(W16 + (long long)(j0 + r) * HID + k0 + c * 8);
            *(uint4*)(sB + r * 128 + swz(r, c * 16)) = v;
        }
        __syncthreads();
#pragma unroll
        for (int ks = 0; ks < 2; ++ks) {
            int kb = ks * 64 + ((lane >> 4) << 4);
            int ar = lane & 15;
            bf16x8 a0 = *(const bf16x8*)(sA + (w * 32 + ar) * 128 + swz(ar, kb));
            bf16x8 a1 = *(const bf16x8*)(sA + (w * 32 + 16 + ar) * 128 + swz(ar, kb));
#pragma unroll
            for (int jf = 0; jf < 4; ++jf) {
                bf16x8 b = *(const bf16x8*)(sB + (jf * 16 + ar) * 128 + swz(ar, kb));
                acc[0][jf] = __builtin_amdgcn_mfma_f32_16x16x32_bf16(a0, b, acc[0][jf], 0, 0, 0);
                acc[1][jf] = __builtin_amdgcn_mfma_f32_16x16x32_bf16(a1, b, acc[1][jf], 0, 0, 0);
            }
        }
        __syncthreads();
    }

#pragma unroll
    for (int jf = 0; jf < 4; ++jf) {
        int j = j0 + jf * 16 + (lane & 15);
        float bv = bias[j];
#pragma unroll
        for (int m = 0; m < 2; ++m) {
#pragma unroll
            for (int q = 0; q < 4; ++q) {
                int row = m0 + w * 32 + m * 16 + (lane >> 4) * 4 + q;
                if (row < M) {
                    float val = acc[m][jf][q] + bv;
                    if (F32OUT) gf[(long long)row * 1536 + j] = val;
                    else        g16[(long long)row * 1536 + j] = f2bf(val);
                }
            }
        }
    }
}

// ---------------------------------------------------------------------------
// h2 table: pair pr = v0*20+v1: h2 = GRU(gx=Gx20[v1], gh=Gh1[v0], hp=H1f[v0])
__global__ __launch_bounds__(256)
void h2_expand(const float* __restrict__ Gx20, const float* __restrict__ Gh1,
               const float* __restrict__ H1f, float* __restrict__ h2f,
               u16* __restrict__ h2_16) {
    int idx = blockIdx.x * 256 + threadIdx.x;   // 400*512
    int pr = idx >> 9, j = idx & 511;
    int v0 = pr / 20, v1 = pr % 20;
    const float* gx = Gx20 + (long long)v1 * 1536 + j;
    const float* gh = Gh1 + (long long)v0 * 1536 + j;
    float r = sigm(gx[0] + gh[0]);
    float z = sigm(gx[512] + gh[512]);
    float cand = tanhf(gx[1024] + r * gh[1024]);
    float h = (1.f - z) * cand + z * H1f[(long long)v0 * HID + j];
    h2f[(long long)pr * HID + j] = h;
    h2_16[(long long)pr * HID + j] = f2bf(h);
}

// h3 per parent: p -> (v0,v1,v2); h3 = GRU(gx=Gx20[v2], gh=Gh2[pr], hp=h2f[pr])
__global__ __launch_bounds__(256)
void h3_expand(const float* __restrict__ Gx20, const float* __restrict__ Gh2,
               const float* __restrict__ h2f, const int* __restrict__ nt,
               float* __restrict__ hdst_f, u16* __restrict__ hdst16) {
    int idx = blockIdx.x * 256 + threadIdx.x;   // 4096*512
    int p = idx >> 9, j = idx & 511;
    int v0 = nt[LEAF + p * 8], v1 = nt[LEAF + p * 8 + 1], v2 = nt[LEAF + p * 8 + 2];
    int pr = v0 * 20 + v1;
    const float* gx = Gx20 + (long long)v2 * 1536 + j;
    const float* gh = Gh2 + (long long)pr * 1536 + j;
    float r = sigm(gx[0] + gh[0]);
    float z = sigm(gx[512] + gh[512]);
    float cand = tanhf(gx[1024] + r * gh[1024]);
    float h = (1.f - z) * cand + z * h2f[(long long)pr * HID + j];
    hdst_f[(long long)p * HID + j] = h;
    hdst16[(long long)p * HID + j] = f2bf(h);
}

// ---------------------------------------------------------------------------
// Fused h-side GRU step, PROWS-row p-tile, async global_load_lds staging.
// LDS stored LINEAR; global source pre-swizzled (col_chunk ^= lane>>3);
// reads use swz() — net effect identical to the old swizzled store.
// REQUIRES n % PROWS == 0 (no row masking on the async path).
template<int GX_TABLE, int PROWS>
__global__ __launch_bounds__(256, 4)
void step32(const u16* __restrict__ hsrc16, const float* __restrict__ hsrc_f,
            const float* __restrict__ Gx20, const u16* __restrict__ gx16, int t,
            const int* __restrict__ nt,
            float* __restrict__ hdst_f, u16* __restrict__ hdst16,
            const u16* __restrict__ Whh16, const float* __restrict__ b_hh, int n) {
    constexpr int MT = PROWS / 16;
    constexpr int ACH = PROWS / 8;        // 1KB chunks for A
    constexpr int TOT = ACH + 24;         // + 3 gates x 8 chunks
    constexpr int NIT = (TOT + 3) / 4;
    __shared__ __align__(16) uint8_t sA[PROWS * 128];
    __shared__ __align__(16) uint8_t sB[3][64 * 128];
    int tid = threadIdx.x, lane = tid & 63, w = tid >> 6;
    int p0 = blockIdx.x * PROWS, j0 = blockIdx.y * 64;
    int ar = lane & 15;
    int rsub = lane >> 3;                 // row within 8-row chunk
    int cswb = ((lane & 7) ^ rsub) * 16;  // pre-swizzled source byte offset

    f32x4 acc[3][MT];
#pragma unroll
    for (int g = 0; g < 3; ++g)
#pragma unroll
        for (int m = 0; m < MT; ++m) acc[g][m] = (f32x4){0.f, 0.f, 0.f, 0.f};

    for (int kt = 0; kt < 8; ++kt) {
        int k0 = kt * 64;
#pragma unroll
        for (int i = 0; i < NIT; ++i) {
            int ch = w + 4 * i;
            if (ch < TOT) {
                const u16* grow;
                uint8_t* ldst;
                if (ch < ACH) {
                    grow = hsrc16 + (long long)(p0 + ch * 8 + rsub) * HID + k0;
                    ldst = sA + ch * 1024;
                } else {
                    int bi = ch - ACH, g = bi >> 3, r8 = bi & 7;
                    grow = Whh16 + (long long)(g * HID + j0 + r8 * 8 + rsub) * HID + k0;
                    ldst = sB[g] + r8 * 1024;
                }
                gload_lds16((const uint8_t*)grow + cswb, ldst);
            }
        }
        __syncthreads();
#pragma unroll
        for (int ks = 0; ks < 2; ++ks) {
            int kb = ks * 64 + ((lane >> 4) << 4);
            bf16x8 a[MT];
#pragma unroll
            for (int m = 0; m < MT; ++m)
                a[m] = *(const bf16x8*)(sA + (m * 16 + ar) * 128 + swz(ar, kb));
#pragma unroll
            for (int g = 0; g < 3; ++g) {
                bf16x8 b = *(const bf16x8*)(sB[g] + (w * 16 + ar) * 128 + swz(ar, kb));
#pragma unroll
                for (int m = 0; m < MT; ++m)
                    acc[g][m] = __builtin_amdgcn_mfma_f32_16x16x32_bf16(a[m], b, acc[g][m], 0, 0, 0);
            }
        }
        __syncthreads();
    }

    int jj = j0 + w * 16 + ar;
    float bhr = b_hh[jj], bhz = b_hh[HID + jj], bhn = b_hh[2 * HID + jj];
#pragma unroll
    for (int m = 0; m < MT; ++m) {
#pragma unroll
        for (int q = 0; q < 4; ++q) {
            int p = p0 + m * 16 + (lane >> 4) * 4 + q;
            if (p >= n) continue;
            float xr, xz, xn;
            if (GX_TABLE) {
                int v = nt[LEAF + p * 8 + t];
                const float* gp = Gx20 + (long long)v * 1536 + jj;
                xr = gp[0]; xz = gp[512]; xn = gp[1024];
            } else {
                long long gb = ((long long)(p * 8 + t)) * 1536 + jj;
                xr = bf2f(gx16[gb]); xz = bf2f(gx16[gb + 512]); xn = bf2f(gx16[gb + 1024]);
            }
            float r = sigm(xr + acc[0][m][q] + bhr);
            float z = sigm(xz + acc[1][m][q] + bhz);
            float cand = tanhf(xn + r * (acc[2][m][q] + bhn));
            float hp = hsrc_f[(long long)p * HID + jj];
            float hnew = (1.f - z) * cand + z * hp;
            hdst_f[(long long)p * HID + jj] = hnew;
            hdst16[(long long)p * HID + jj] = f2bf(hnew);
        }
    }
}

// ---------------------------------------------------------------------------
// Combine, PROWS-row p-tile, async staging (same scheme). n % PROWS == 0.
template<int PROWS>
__global__ __launch_bounds__(256, 4)
void combine32(const u16* __restrict__ enc_in, const u16* __restrict__ Wch16,
               const int* __restrict__ nt, int off, const float* __restrict__ Pe,
               u16* __restrict__ out16, int n) {
    constexpr int MT = PROWS / 16;
    constexpr int ACH = PROWS / 8;
    constexpr int TOT = ACH + 8;
    constexpr int NIT = (TOT + 3) / 4;
    __shared__ __align__(16) uint8_t sA[PROWS * 128];
    __shared__ __align__(16) uint8_t sB[64 * 128];
    int tid = threadIdx.x, lane = tid & 63, w = tid >> 6;
    int p0 = blockIdx.x * PROWS, j0 = blockIdx.y * 64;
    int ar = lane & 15;
    int rsub = lane >> 3;
    int cswb = ((lane & 7) ^ rsub) * 16;

    f32x4 acc[MT];
#pragma unroll
    for (int m = 0; m < MT; ++m) acc[m] = (f32x4){0.f, 0.f, 0.f, 0.f};

    for (int kt = 0; kt < 8; ++kt) {
        int k0 = kt * 64;
#pragma unroll
        for (int i = 0; i < NIT; ++i) {
            int ch = w + 4 * i;
            if (ch < TOT) {
                const u16* grow;
                uint8_t* ldst;
                if (ch < ACH) {
                    grow = enc_in + (long long)(p0 + ch * 8 + rsub) * HID + k0;
                    ldst = sA + ch * 1024;
                } else {
                    int r8 = ch - ACH;
                    grow = Wch16 + (long long)(j0 + r8 * 8 + rsub) * HID + k0;
                    ldst = sB + r8 * 1024;
                }
                gload_lds16((const uint8_t*)grow + cswb, ldst);
            }
        }
        __syncthreads();
#pragma unroll
        for (int ks = 0; ks < 2; ++ks) {
            int kb = ks * 64 + ((lane >> 4) << 4);
            bf16x8 b = *(const bf16x8*)(sB + (w * 16 + ar) * 128 + swz(ar, kb));
#pragma unroll
            for (int m = 0; m < MT; ++m) {
                bf16x8 a = *(const bf16x8*)(sA + (m * 16 + ar) * 128 + swz(ar, kb));
                acc[m] = __builtin_amdgcn_mfma_f32_16x16x32_bf16(a, b, acc[m], 0, 0, 0);
            }
        }
        __syncthreads();
    }

    int jj = j0 + w * 16 + ar;
#pragma unroll
    for (int m = 0; m < MT; ++m) {
#pragma unroll
        for (int q = 0; q < 4; ++q) {
            int p = p0 + m * 16 + (lane >> 4) * 4 + q;
            if (p >= n) continue;
            int tv = nt[off + p];
            float v = tanhf(Pe[(long long)tv * HID + jj] + acc[m][q]);
            out16[(long long)p * HID + jj] = f2bf(v);
        }
    }
}

// ---------------------------------------------------------------------------
// Step t=0 (h=0): h1 = (1-z)*cand from gx row. One thread per (p,j).
__global__ __launch_bounds__(256)
void t0_simt(const u16* __restrict__ gx16, const float* __restrict__ b_hh,
             float* __restrict__ hdst_f, u16* __restrict__ hdst16, int n) {
    int idx = blockIdx.x * 256 + threadIdx.x;
    int p = idx >> 9, j = idx & 511;
    if (p >= n) return;
    long long gb = ((long long)(p * 8)) * 1536 + j;
    float xr = bf2f(gx16[gb]), xz = bf2f(gx16[gb + 512]), xn = bf2f(gx16[gb + 1024]);
    float r = sigm(xr + b_hh[j]);
    float z = sigm(xz + b_hh[HID + j]);
    float cand = tanhf(xn + r * b_hh[2 * HID + j]);
    float h = (1.f - z) * cand;
    hdst_f[(long long)p * HID + j] = h;
    hdst16[(long long)p * HID + j] = f2bf(h);
}

// K-split SIMT GRU step (n <= 64)
__global__ __launch_bounds__(256)
void step_simt(const u16* __restrict__ gx16, int t,
               const float* __restrict__ hsrc_f, const u16* __restrict__ hsrc16,
               float* __restrict__ hdst_f, u16* __restrict__ hdst16,
               const u16* __restrict__ Whh16, const float* __restrict__ b_hh, int n) {
    int idx = blockIdx.x * 256 + threadIdx.x;
    int kc = idx & 3, pj = idx >> 2;
    int p = pj >> 9, j = pj & 511;
    if (p >= n) return;
    const u16* hp16 = hsrc16 + (long long)p * HID + kc * 128;
    const u16* w0 = Whh16 + (long long)j * HID + kc * 128;
    const u16* w1 = w0 + (long long)HID * HID;
    const u16* w2 = w1 + (long long)HID * HID;
    float a0 = 0.f, a1 = 0.f, a2 = 0.f;
#pragma unroll 4
    for (int k = 0; k < 128; k += 8) {
        bf16x8 hv = *(const bf16x8*)(hp16 + k);
        bf16x8 v0 = *(const bf16x8*)(w0 + k);
        bf16x8 v1 = *(const bf16x8*)(w1 + k);
        bf16x8 v2 = *(const bf16x8*)(w2 + k);
#pragma unroll
        for (int i = 0; i < 8; ++i) {
            float hh = bf2f((u16)hv[i]);
            a0 += hh * bf2f((u16)v0[i]);
            a1 += hh * bf2f((u16)v1[i]);
            a2 += hh * bf2f((u16)v2[i]);
        }
    }
    a0 += __shfl_xor(a0, 1); a0 += __shfl_xor(a0, 2);
    a1 += __shfl_xor(a1, 1); a1 += __shfl_xor(a1, 2);
    a2 += __shfl_xor(a2, 1); a2 += __shfl_xor(a2, 2);
    if (kc == 0) {
        long long gb = ((long long)(p * 8 + t)) * 1536 + j;
        float xr = bf2f(gx16[gb]), xz = bf2f(gx16[gb + 512]), xn = bf2f(gx16[gb + 1024]);
        float r = sigm(xr + a0 + b_hh[j]);
        float z = sigm(xz + a1 + b_hh[HID + j]);
        float cand = tanhf(xn + r * (a2 + b_hh[2 * HID + j]));
        float hp = hsrc_f[(long long)p * HID + j];
        float hnew = (1.f - z) * cand + z * hp;
        hdst_f[(long long)p * HID + j] = hnew;
        hdst16[(long long)p * HID + j] = f2bf(hnew);
    }
}

// K-split SIMT combine (n <= 64)
__global__ __launch_bounds__(256)
void combine_simt(const u16* __restrict__ h16, const u16* __restrict__ Wch16,
                  const int* __restrict__ nt, int off, const float* __restrict__ Pe,
                  u16* __restrict__ enc16, float* __restrict__ outf, int n) {
    int idx = blockIdx.x * 256 + threadIdx.x;
    int kc = idx & 3, pj = idx >> 2;
    int p = pj >> 9, j = pj & 511;
    if (p >= n) return;
    const u16* hp = h16 + (long long)p * HID + kc * 128;
    const u16* wr = Wch16 + (long long)j * HID + kc * 128;
    float a = 0.f;
#pragma unroll 4
    for (int k = 0; k < 128; k += 8) {
        bf16x8 hv = *(const bf16x8*)(hp + k);
        bf16x8 wv = *(const bf16x8*)(wr + k);
#pragma unroll
        for (int i = 0; i < 8; ++i) a += bf2f((u16)hv[i]) * bf2f((u16)wv[i]);
    }
    a += __shfl_xor(a, 1); a += __shfl_xor(a, 2);
    if (kc == 0) {
        int tv = nt[off + p];
        float v = tanhf(Pe[(long long)tv * HID + j] + a);
        enc16[(long long)p * HID + j] = f2bf(v);
        if (outf) outf[(long long)p * HID + j] = v;
    }
}

// ---------------------------------------------------------------------------
extern "C" void kernel_launch(void* const* d_in, const int* in_sizes, int n_in,
                              void* d_out, int out_size, void* d_ws, size_t ws_size,
                              hipStream_t stream) {
    const int*   nt   = (const int*)d_in[0];
    const float* emb  = (const float*)d_in[1];
    const float* Wc_w = (const float*)d_in[2];
    const float* Wc_b = (const float*)d_in[3];
    const float* W_ih = (const float*)d_in[4];
    const float* W_hh = (const float*)d_in[5];
    const float* b_ih = (const float*)d_in[6];
    const float* b_hh = (const float*)d_in[7];

    uint8_t* p = (uint8_t*)d_ws;
    u16*   gx16  = (u16*)p;   p += (size_t)4096 * 1536 * 2;    // levels 3..0
    u16*   enc16 = (u16*)p;   p += (size_t)4096 * HID * 2;
    float* hf[2]; u16* h16[2];
    hf[0]  = (float*)p; p += (size_t)4096 * HID * 4;
    hf[1]  = (float*)p; p += (size_t)4096 * HID * 4;
    h16[0] = (u16*)p;   p += (size_t)4096 * HID * 2;
    h16[1] = (u16*)p;   p += (size_t)4096 * HID * 2;
    u16*   Wih16 = (u16*)p;   p += (size_t)3 * HID * HID * 2;
    u16*   Whh16 = (u16*)p;   p += (size_t)3 * HID * HID * 2;
    u16*   Wch16 = (u16*)p;   p += (size_t)HID * HID * 2;
    float* Pe    = (float*)p; p += (size_t)20 * HID * 4;
    u16*   PeT16 = (u16*)p;   p += (size_t)20 * HID * 2;
    float* Gx20  = (float*)p; p += (size_t)20 * 1536 * 4;
    float* H1f   = (float*)p; p += (size_t)20 * HID * 4;
    u16*   H1_16 = (u16*)p;   p += (size_t)20 * HID * 2;
    float* Gh1   = (float*)p; p += (size_t)20 * 1536 * 4;
    float* Gh2   = (float*)p; p += (size_t)400 * 1536 * 4;
    float* h2f   = (float*)p; p += (size_t)400 * HID * 4;
    u16*   h2_16 = (u16*)p;   p += (size_t)400 * HID * 2;

    // prologue (3 nodes)
    conv_pe<<<532, 512, 0, stream>>>(W_ih, W_hh, Wc_w, emb, Wc_b,
                                     Wih16, Whh16, Wch16, Pe, PeT16);
    gx20_kernel<<<dim3(20, 6), 256, 0, stream>>>(PeT16, Wih16, b_ih, Gx20);
    h1_kernel<<<20, 512, 0, stream>>>(Gx20, b_hh, H1f, H1_16);

    // ---- level 4 (n = 4096): t=0,1,2 via alphabet tables; t=3..7 fused MFMA ----
    {
        int n = 4096;
        gx_gemm<true><<<dim3(24, 1), 256, 0, stream>>>(H1_16, Whh16, b_hh, nullptr, Gh1, 20);
        h2_expand<<<800, 256, 0, stream>>>(Gx20, Gh1, H1f, h2f, h2_16);
        gx_gemm<true><<<dim3(24, 4), 256, 0, stream>>>(h2_16, Whh16, b_hh, nullptr, Gh2, 400);
        h3_expand<<<8192, 256, 0, stream>>>(Gx20, Gh2, h2f, nt, hf[0], h16[0]);
        int cur = 0;
        dim3 sgrid(n / 32, 8);   // PROWS=32: measured-best (4 blocks/CU)
        for (int t = 3; t < 8; ++t) {
            step32<1, 32><<<sgrid, 256, 0, stream>>>(h16[cur], hf[cur], Gx20, nullptr, t, nt,
                                                     hf[cur ^ 1], h16[cur ^ 1], Whh16, b_hh, n);
            cur ^= 1;
        }
        combine32<32><<<sgrid, 256, 0, stream>>>(h16[cur], Wch16, nt, 585, Pe, enc16, n);
    }

    // ---- levels 3..0 ----
    const int sizes[4] = {512, 64, 8, 1};
    const int offs[4]  = {73, 9, 1, 0};
    for (int li = 0; li < 4; ++li) {
        int n = sizes[li], off = offs[li];
        int M = n * 8;
        dim3 ggrid(24, (M + 127) / 128);
        gx_gemm<false><<<ggrid, 256, 0, stream>>>(enc16, Wih16, b_ih, gx16, nullptr, M);

        t0_simt<<<n * 2, 256, 0, stream>>>(gx16, b_hh, hf[0], h16[0], n);
        int cur = 0;
        if (n >= 512) {
            dim3 sgrid(n / 16, 8);   // PROWS=16 -> 256 blocks
            for (int t = 1; t < 8; ++t) {
                step32<0, 16><<<sgrid, 256, 0, stream>>>(h16[cur], hf[cur], nullptr, gx16, t, nt,
                                                         hf[cur ^ 1], h16[cur ^ 1], Whh16, b_hh, n);
                cur ^= 1;
            }
            combine32<16><<<sgrid, 256, 0, stream>>>(h16[cur], Wch16, nt, off, Pe, enc16, n);
        } else {
            for (int t = 1; t < 8; ++t) {
                step_simt<<<n * 8, 256, 0, stream>>>(gx16, t, hf[cur], h16[cur],
                                                     hf[cur ^ 1], h16[cur ^ 1], Whh16, b_hh, n);
                cur ^= 1;
            }
            combine_simt<<<n * 8, 256, 0, stream>>>(h16[cur], Wch16, nt, off, Pe, enc16,
                                                    (li == 3) ? (float*)d_out : (float*)0, n);
        }
    }
}